// Round 6
// baseline (157.486 us; speedup 1.0000x reference)
//
#include <hip/hip_runtime.h>

#define NBK 10
#define KK  9
#define SC_AGENT __HIP_MEMORY_SCOPE_AGENT

constexpr int Bv  = 4;
constexpr int Vv  = 5023;
constexpr int TOT = Bv * Vv;        // 20092
constexpr int UXP = 12;             // padded ux row stride
constexpr int NBLK_F = 628;         // fused grid
constexpr int GRPB = (Vv + 15) / 16;   // 314 groups per batch
// per-batch strides (floats), 256B aligned -> no cross-XCD shared dirty lines
constexpr int HS16 = ((Vv * 16 + 63) / 64) * 64;   // 80384
constexpr int HS32 = ((Vv * 32 + 63) / 64) * 64;   // 160768
constexpr int UXS  = ((Vv * UXP + 63) / 64) * 64;  // 60288

// ---------------------------------------------------------------------------
// Control block in d_ws (zeroed by captured hipMemsetAsync each call).
// All barrier ops are RELAXED atomics (single L3 op, no L2 inv/wb storms).
// ---------------------------------------------------------------------------
struct BarR {                        // split-16 barrier (global, 628 blocks)
    int lo[16 * 32];
    int hi;   int p1[31];
    int flag; int p2[31];
};
struct BarS {                        // single-counter barrier (per batch)
    int cnt;  int p1[31];
    int flag; int p2[31];
};
struct Ctrl {
    BarR reg;          // registration barrier
    int  cnt[8 * 32];  // per-XCD block counters (128B apart)
    BarS lb[5][4];     // [layer][batch] barriers for mode path
    BarR fb[5];        // global barriers for fallback path
};

__device__ __forceinline__ void barR_sync(BarR* bar, int bid, int tid)
{
    __syncthreads();   // per-wave vmcnt(0) before s_barrier -> stores drained
    if (tid == 0) {
        const int g    = bid & 15;
        const int need = (NBLK_F >> 4) + ((g < (NBLK_F & 15)) ? 1 : 0);
        const int old = __hip_atomic_fetch_add(&bar->lo[g * 32], 1,
                                               __ATOMIC_RELAXED, SC_AGENT);
        if (old == need - 1) {
            const int oh = __hip_atomic_fetch_add(&bar->hi, 1,
                                                  __ATOMIC_RELAXED, SC_AGENT);
            if (oh == 15)
                __hip_atomic_store(&bar->flag, 1, __ATOMIC_RELAXED, SC_AGENT);
        }
        while (__hip_atomic_load(&bar->flag, __ATOMIC_RELAXED, SC_AGENT) == 0)
            __builtin_amdgcn_s_sleep(2);
    }
    __syncthreads();
}

__device__ __forceinline__ void barS_sync(BarS* bar, int need, int tid)
{
    __syncthreads();
    if (tid == 0) {
        const int old = __hip_atomic_fetch_add(&bar->cnt, 1,
                                               __ATOMIC_RELAXED, SC_AGENT);
        if (old == need - 1)
            __hip_atomic_store(&bar->flag, 1, __ATOMIC_RELAXED, SC_AGENT);
        while (__hip_atomic_load(&bar->flag, __ATOMIC_RELAXED, SC_AGENT) == 0)
            __builtin_amdgcn_s_sleep(2);
    }
    __syncthreads();
}

// COH=true: L2-bypassing (coherent-at-L3) access. COH=false: normal cached.
template<bool COH>
__device__ __forceinline__ float ldf(const float* p)
{
    if constexpr (COH) return __hip_atomic_load(p, __ATOMIC_RELAXED, SC_AGENT);
    else               return *p;
}
template<bool COH>
__device__ __forceinline__ void stf(float* p, float v)
{
    if constexpr (COH) __hip_atomic_store(p, v, __ATOMIC_RELAXED, SC_AGENT);
    else               *p = v;
}

// ---------------------------------------------------------------------------
__device__ __forceinline__ float merge16(float* a, int t)
{
#pragma unroll
    for (int j = 0; j < 8; j++) {
        float send = (t & 8) ? a[j] : a[j + 8];
        float keep = (t & 8) ? a[j + 8] : a[j];
        a[j] = keep + __shfl_xor(send, 8, 16);
    }
#pragma unroll
    for (int j = 0; j < 4; j++) {
        float send = (t & 4) ? a[j] : a[j + 4];
        float keep = (t & 4) ? a[j + 4] : a[j];
        a[j] = keep + __shfl_xor(send, 4, 16);
    }
#pragma unroll
    for (int j = 0; j < 2; j++) {
        float send = (t & 2) ? a[j] : a[j + 2];
        float keep = (t & 2) ? a[j + 2] : a[j];
        a[j] = keep + __shfl_xor(send, 2, 16);
    }
    {
        float send = (t & 1) ? a[0] : a[1];
        float keep = (t & 1) ? a[1] : a[0];
        a[0] = keep + __shfl_xor(send, 1, 16);
    }
    return a[0];
}

// ---------------------------------------------------------------------------
// Tail: G-phase, E-phase, merge, epilogue. All pointers batch-local.
// dout is ALWAYS write-through (batch boundary lines shared across XCDs).
// ---------------------------------------------------------------------------
template<int CIN, int COUT, bool LAST, bool COH>
__device__ __forceinline__ void nlayer_tail(
    bool act, int lv, int t, float rec,
    const float* hn0, const float* hn1, const float* q,
    const float* __restrict__ W, const float* __restrict__ bvec,
    const float* __restrict__ unx,
    float* __restrict__ houtB, float* __restrict__ uxoutB, float* __restrict__ doutB)
{
    float g0[KK], g1[KK];
#pragma unroll
    for (int k = 0; k < KK; k++) { g0[k] = 0.0f; g1[k] = 0.0f; }
#pragma unroll
    for (int n = 0; n < NBK; n++) {
#pragma unroll
        for (int k = 0; k < KK; k++) {
            const float qnk = __shfl(q[k], n, 16);
            g0[k] = fmaf(qnk, hn0[n], g0[k]);
            if constexpr (CIN == 32) g1[k] = fmaf(qnk, hn1[n], g1[k]);
        }
    }

    if constexpr (!LAST) {
        float acc[COUT] = {};
#pragma unroll
        for (int k = 0; k < KK; k++) {
            const float4* wr = reinterpret_cast<const float4*>(&W[((size_t)t * KK + k) * COUT]);
#pragma unroll
            for (int o4 = 0; o4 < COUT / 4; o4++) {
                const float4 w = wr[o4];
                acc[4 * o4 + 0] = fmaf(g0[k], w.x, acc[4 * o4 + 0]);
                acc[4 * o4 + 1] = fmaf(g0[k], w.y, acc[4 * o4 + 1]);
                acc[4 * o4 + 2] = fmaf(g0[k], w.z, acc[4 * o4 + 2]);
                acc[4 * o4 + 3] = fmaf(g0[k], w.w, acc[4 * o4 + 3]);
            }
            if constexpr (CIN == 32) {
                const float4* wr2 = reinterpret_cast<const float4*>(&W[((size_t)(t + 16) * KK + k) * COUT]);
#pragma unroll
                for (int o4 = 0; o4 < COUT / 4; o4++) {
                    const float4 w = wr2[o4];
                    acc[4 * o4 + 0] = fmaf(g1[k], w.x, acc[4 * o4 + 0]);
                    acc[4 * o4 + 1] = fmaf(g1[k], w.y, acc[4 * o4 + 1]);
                    acc[4 * o4 + 2] = fmaf(g1[k], w.z, acc[4 * o4 + 2]);
                    acc[4 * o4 + 3] = fmaf(g1[k], w.w, acc[4 * o4 + 3]);
                }
            }
        }

        float o0 = merge16(acc, t);
        float h0v = fmaxf(fmaf(o0, rec, bvec[t]), 0.0f);
        float h1v = 0.0f;
        if (act) stf<COH>(&houtB[(size_t)lv * COUT + t], h0v);
        if constexpr (COUT == 32) {
            float o1 = merge16(acc + 16, t);
            h1v = fmaxf(fmaf(o1, rec, bvec[t + 16]), 0.0f);
            if (act) stf<COH>(&houtB[(size_t)lv * COUT + 16 + t], h1v);
        }

        float uxv = 0.0f;
#pragma unroll
        for (int o = 0; o < 16; o++) {
            const float hb = __shfl(h0v, o, 16);
            if (t < KK) uxv = fmaf(hb, unx[o * KK + t], uxv);
        }
        if constexpr (COUT == 32) {
#pragma unroll
            for (int o = 0; o < 16; o++) {
                const float hb = __shfl(h1v, o, 16);
                if (t < KK) uxv = fmaf(hb, unx[(o + 16) * KK + t], uxv);
            }
        }
        if (act && t < KK) stf<COH>(&uxoutB[(size_t)lv * UXP + t], uxv);
    } else {
        float acc[3] = {};
#pragma unroll
        for (int k = 0; k < KK; k++) {
            const float* wr = &W[((size_t)t * KK + k) * 3];
            acc[0] = fmaf(g0[k], wr[0], acc[0]);
            acc[1] = fmaf(g0[k], wr[1], acc[1]);
            acc[2] = fmaf(g0[k], wr[2], acc[2]);
        }
#pragma unroll
        for (int o = 0; o < 3; o++) {
            acc[o] += __shfl_xor(acc[o], 1, 16);
            acc[o] += __shfl_xor(acc[o], 2, 16);
            acc[o] += __shfl_xor(acc[o], 4, 16);
            acc[o] += __shfl_xor(acc[o], 8, 16);
        }
        float hnew[3];
#pragma unroll
        for (int o = 0; o < 3; o++)
            hnew[o] = fmaxf(fmaf(acc[o], rec, bvec[o]), 0.0f);
        if (act && t < 3) {
            float s = 0.0f;
#pragma unroll
            for (int j = 0; j < 3; j++)
                s = fmaf(hnew[j], unx[j * 3 + t], s);
            stf<true>(&doutB[(size_t)lv * 3 + t], s);   // always write-through
        }
    }
}

// ---------------------------------------------------------------------------
template<int CIN, int COUT, bool LAST, bool COH>
__device__ __forceinline__ void nlayer_step(
    bool act, int lv, int t, const int* nb, float rec,
    const float* __restrict__ hinB, const float* __restrict__ uxinB,
    const float* __restrict__ W, const float* __restrict__ bvec,
    const float* __restrict__ cvec, const float* __restrict__ unx,
    float* __restrict__ houtB, float* __restrict__ uxoutB, float* __restrict__ doutB)
{
    float hn0[NBK], hn1[NBK];
#pragma unroll
    for (int n = 0; n < NBK; n++) {
        const int a = nb[n];
        const float* hb = &hinB[(size_t)(a - 1) * CIN];
        hn0[n] = a ? ldf<COH>(hb + t) : 0.0f;
        if constexpr (CIN == 32) hn1[n] = a ? ldf<COH>(hb + t + 16) : 0.0f;
        else                     hn1[n] = 0.0f;
    }

    float q[KK] = {};
    if (act && t < NBK) {
        const float* su = &uxinB[(size_t)lv * UXP];
        const int a = nb[t];
        const float* nu = a ? &uxinB[(size_t)(a - 1) * UXP] : nullptr;
        float lg[KK];
#pragma unroll
        for (int k = 0; k < KK; k++) {
            const float own = ldf<COH>(su + k);
            const float nbu = a ? ldf<COH>(nu + k) : 0.0f;
            lg[k] = own + nbu + cvec[k];
        }
        float m = lg[0];
#pragma unroll
        for (int k = 1; k < KK; k++) m = fmaxf(m, lg[k]);
        float sum = 0.0f;
#pragma unroll
        for (int k = 0; k < KK; k++) { q[k] = __expf(lg[k] - m); sum += q[k]; }
        const float r = 1.0f / sum;
#pragma unroll
        for (int k = 0; k < KK; k++) q[k] *= r;
    }

    nlayer_tail<CIN, COUT, LAST, COH>(act, lv, t, rec, hn0, hn1, q,
                                      W, bvec, unx, houtB, uxoutB, doutB);
}

// ---------------------------------------------------------------------------
// Layer 0 with encoder folded (verified round 5): h0 recomputed from x.
// ---------------------------------------------------------------------------
template<bool COH>
__device__ __forceinline__ void layer0_step(
    bool act, int lv, int t, const int* nb, float rec,
    const float* __restrict__ xB, const float* __restrict__ Win,
    const float* __restrict__ u0,
    const float* __restrict__ W, const float* __restrict__ bvec,
    const float* __restrict__ cvec, const float* __restrict__ unx,
    float* __restrict__ houtB, float* __restrict__ uxoutB)
{
    const float w0 = Win[t], w1 = Win[16 + t], w2 = Win[32 + t];
    float hn0[NBK], hn1[NBK];
#pragma unroll
    for (int n = 0; n < NBK; n++) {
        const int a = nb[n];
        float x0 = 0.f, x1 = 0.f, x2 = 0.f;
        if (a) {
            const float* xr = &xB[(size_t)(a - 1) * 3];
            x0 = xr[0]; x1 = xr[1]; x2 = xr[2];
        }
        hn0[n] = fmaxf(x0 * w0 + x1 * w1 + x2 * w2, 0.0f);
        hn1[n] = 0.0f;
    }

    float q[KK] = {};
    if (act && t < NBK) {
        const float* xo = &xB[(size_t)lv * 3];
        const float xo0 = xo[0], xo1 = xo[1], xo2 = xo[2];
        const int a = nb[t];
        float xn0 = 0.f, xn1 = 0.f, xn2 = 0.f;
        if (a) {
            const float* xr = &xB[(size_t)(a - 1) * 3];
            xn0 = xr[0]; xn1 = xr[1]; xn2 = xr[2];
        }
        float hs[16];
#pragma unroll
        for (int c = 0; c < 16; c++) {
            const float ho = fmaxf(xo0 * Win[c] + xo1 * Win[16 + c] + xo2 * Win[32 + c], 0.0f);
            const float hn = fmaxf(xn0 * Win[c] + xn1 * Win[16 + c] + xn2 * Win[32 + c], 0.0f);
            hs[c] = ho + hn;
        }
        float lg[KK];
#pragma unroll
        for (int k = 0; k < KK; k++) {
            float s = cvec[k];
#pragma unroll
            for (int c = 0; c < 16; c++) s = fmaf(hs[c], u0[c * KK + k], s);
            lg[k] = s;
        }
        float m = lg[0];
#pragma unroll
        for (int k = 1; k < KK; k++) m = fmaxf(m, lg[k]);
        float sum = 0.0f;
#pragma unroll
        for (int k = 0; k < KK; k++) { q[k] = __expf(lg[k] - m); sum += q[k]; }
        const float r = 1.0f / sum;
#pragma unroll
        for (int k = 0; k < KK; k++) q[k] *= r;
    }

    nlayer_tail<16, 16, false, COH>(act, lv, t, rec, hn0, hn1, q,
                                    W, bvec, unx, houtB, uxoutB, nullptr);
}

// ---------------------------------------------------------------------------
__device__ __forceinline__ void load_group(
    const int* __restrict__ adj, int lv, bool act, int* nb, float& rec)
{
    if (act) {
        const int2* arow = reinterpret_cast<const int2*>(&adj[lv * NBK]);
#pragma unroll
        for (int j = 0; j < 5; j++) { int2 p = arow[j]; nb[2 * j] = p.x; nb[2 * j + 1] = p.y; }
    } else {
#pragma unroll
        for (int n = 0; n < NBK; n++) nb[n] = 0;
    }
    int cnt = 0;
#pragma unroll
    for (int n = 0; n < NBK; n++) cnt += (nb[n] != 0) ? 1 : 0;
    rec = cnt ? (1.0f / (float)cnt) : 0.0f;
}

struct KArgs {
    const float* x; const int* adj; const float* Win; const float* Wout;
    const float* W[6]; const float* bv[6]; const float* uv[6]; const float* cv[6];
    Ctrl* C;
    float* h1; float* h2; float* h3; float* h4; float* h5;
    float* u1; float* u2; float* u3; float* u4; float* u5;
    float* out;
};

#define MODE_LAYER(STEPCALL)                                                  \
    for (int grp = start; grp < GRPB; grp += step) {                          \
        const int lv = grp * 16 + g;                                          \
        const bool act = lv < Vv;                                             \
        int nb[NBK]; float rec;                                               \
        load_group(A.adj, act ? lv : 0, act, nb, rec);                        \
        STEPCALL;                                                             \
    }

__global__ __launch_bounds__(256, 3) void fused_kernel(KArgs A)
{
    const int tid = threadIdx.x;
    const int bid = blockIdx.x;
    const int g = tid >> 4;
    const int t = tid & 15;
    Ctrl* C = A.C;

    __shared__ int s_rank, s_step, s_xcd, s_mode;

    // ---- registration: claim rank on my physical XCD ----
    if (tid == 0) {
        int xcd;
        asm volatile("s_getreg_b32 %0, hwreg(HW_REG_XCC_ID)" : "=s"(xcd));
        xcd &= 7;
        const int r = __hip_atomic_fetch_add(&C->cnt[xcd * 32], 1,
                                             __ATOMIC_RELAXED, SC_AGENT);
        asm volatile("s_waitcnt vmcnt(0)" ::: "memory");
        const int sg = bid & 15;
        const int nd = (NBLK_F >> 4) + ((sg < (NBLK_F & 15)) ? 1 : 0);
        const int old = __hip_atomic_fetch_add(&C->reg.lo[sg * 32], 1,
                                               __ATOMIC_RELAXED, SC_AGENT);
        if (old == nd - 1) {
            const int oh = __hip_atomic_fetch_add(&C->reg.hi, 1,
                                                  __ATOMIC_RELAXED, SC_AGENT);
            if (oh == 15)
                __hip_atomic_store(&C->reg.flag, 1, __ATOMIC_RELAXED, SC_AGENT);
        }
        while (__hip_atomic_load(&C->reg.flag, __ATOMIC_RELAXED, SC_AGENT) == 0)
            __builtin_amdgcn_s_sleep(2);
        int ok = 1;
        for (int bb = 0; bb < 4; bb++)
            ok &= (__hip_atomic_load(&C->cnt[bb * 32], __ATOMIC_RELAXED, SC_AGENT) > 0);
        s_rank = r;
        s_xcd  = xcd;
        s_mode = ok;
        s_step = (xcd < 4) ? __hip_atomic_load(&C->cnt[xcd * 32], __ATOMIC_RELAXED, SC_AGENT) : 0;
    }
    __syncthreads();

    if (s_mode) {
        // ===== XCD-partitioned: batch = my XCD; h/ux normal cached (L2-local) =====
        const int xcd = s_xcd;
        if (xcd >= 4) return;
        const int batch = xcd;
        const int start = s_rank;
        const int step  = s_step;
        const int need  = s_step;

        const float* xB = A.x + (size_t)batch * Vv * 3;
        float* doutB    = A.out + (size_t)batch * Vv * 3;
        float* h1 = A.h1 + (size_t)batch * HS16;
        float* h2 = A.h2 + (size_t)batch * HS16;
        float* h3 = A.h3 + (size_t)batch * HS32;
        float* h4 = A.h4 + (size_t)batch * HS16;
        float* h5 = A.h5 + (size_t)batch * HS16;
        float* u1 = A.u1 + (size_t)batch * UXS;
        float* u2 = A.u2 + (size_t)batch * UXS;
        float* u3 = A.u3 + (size_t)batch * UXS;
        float* u4 = A.u4 + (size_t)batch * UXS;
        float* u5 = A.u5 + (size_t)batch * UXS;

        MODE_LAYER((layer0_step<false>(act, lv, t, nb, rec, xB, A.Win, A.uv[0],
                    A.W[0], A.bv[0], A.cv[0], A.uv[1], h1, u1)));
        barS_sync(&C->lb[0][batch], need, tid);
        MODE_LAYER((nlayer_step<16, 16, false, false>(act, lv, t, nb, rec, h1, u1,
                    A.W[1], A.bv[1], A.cv[1], A.uv[2], h2, u2, nullptr)));
        barS_sync(&C->lb[1][batch], need, tid);
        MODE_LAYER((nlayer_step<16, 32, false, false>(act, lv, t, nb, rec, h2, u2,
                    A.W[2], A.bv[2], A.cv[2], A.uv[3], h3, u3, nullptr)));
        barS_sync(&C->lb[2][batch], need, tid);
        MODE_LAYER((nlayer_step<32, 16, false, false>(act, lv, t, nb, rec, h3, u3,
                    A.W[3], A.bv[3], A.cv[3], A.uv[4], h4, u4, nullptr)));
        barS_sync(&C->lb[3][batch], need, tid);
        MODE_LAYER((nlayer_step<16, 16, false, false>(act, lv, t, nb, rec, h4, u4,
                    A.W[4], A.bv[4], A.cv[4], A.uv[5], h5, u5, nullptr)));
        barS_sync(&C->lb[4][batch], need, tid);
        MODE_LAYER((nlayer_step<16, 3, true, false>(act, lv, t, nb, rec, h5, u5,
                    A.W[5], A.bv[5], A.cv[5], A.Wout, nullptr, nullptr, doutB)));
    } else {
        // ===== fallback: verified round-5 bypass path (global barriers) =====
        int   nbA[2][NBK];
        float recA[2];
        int   bA[2], lvA[2];
        bool  actA[2];
#pragma unroll
        for (int it = 0; it < 2; ++it) {
            const int grp = bid * 2 + it;
            const int vv  = grp * 16 + g;
            actA[it] = (vv < TOT);
            int b = 0, lv = 0;
            if (actA[it]) { b = vv / Vv; lv = vv - b * Vv; }
            bA[it] = b; lvA[it] = lv;
            load_group(A.adj, lv, actA[it], nbA[it], recA[it]);
        }

        for (int it = 0; it < 2; ++it) {
            const int b = bA[it];
            layer0_step<true>(actA[it], lvA[it], t, nbA[it], recA[it],
                A.x + (size_t)b * Vv * 3, A.Win, A.uv[0],
                A.W[0], A.bv[0], A.cv[0], A.uv[1],
                A.h1 + (size_t)b * HS16, A.u1 + (size_t)b * UXS);
        }
        barR_sync(&C->fb[0], bid, tid);
        for (int it = 0; it < 2; ++it) {
            const int b = bA[it];
            nlayer_step<16, 16, false, true>(actA[it], lvA[it], t, nbA[it], recA[it],
                A.h1 + (size_t)b * HS16, A.u1 + (size_t)b * UXS,
                A.W[1], A.bv[1], A.cv[1], A.uv[2],
                A.h2 + (size_t)b * HS16, A.u2 + (size_t)b * UXS, nullptr);
        }
        barR_sync(&C->fb[1], bid, tid);
        for (int it = 0; it < 2; ++it) {
            const int b = bA[it];
            nlayer_step<16, 32, false, true>(actA[it], lvA[it], t, nbA[it], recA[it],
                A.h2 + (size_t)b * HS16, A.u2 + (size_t)b * UXS,
                A.W[2], A.bv[2], A.cv[2], A.uv[3],
                A.h3 + (size_t)b * HS32, A.u3 + (size_t)b * UXS, nullptr);
        }
        barR_sync(&C->fb[2], bid, tid);
        for (int it = 0; it < 2; ++it) {
            const int b = bA[it];
            nlayer_step<32, 16, false, true>(actA[it], lvA[it], t, nbA[it], recA[it],
                A.h3 + (size_t)b * HS32, A.u3 + (size_t)b * UXS,
                A.W[3], A.bv[3], A.cv[3], A.uv[4],
                A.h4 + (size_t)b * HS16, A.u4 + (size_t)b * UXS, nullptr);
        }
        barR_sync(&C->fb[3], bid, tid);
        for (int it = 0; it < 2; ++it) {
            const int b = bA[it];
            nlayer_step<16, 16, false, true>(actA[it], lvA[it], t, nbA[it], recA[it],
                A.h4 + (size_t)b * HS16, A.u4 + (size_t)b * UXS,
                A.W[4], A.bv[4], A.cv[4], A.uv[5],
                A.h5 + (size_t)b * HS16, A.u5 + (size_t)b * UXS, nullptr);
        }
        barR_sync(&C->fb[4], bid, tid);
        for (int it = 0; it < 2; ++it) {
            const int b = bA[it];
            nlayer_step<16, 3, true, true>(actA[it], lvA[it], t, nbA[it], recA[it],
                A.h5 + (size_t)b * HS16, A.u5 + (size_t)b * UXS,
                A.W[5], A.bv[5], A.cv[5], A.Wout,
                nullptr, nullptr, A.out + (size_t)b * Vv * 3);
        }
    }
}

// ===========================================================================
// Host-side fallback (co-residency check fails): verified 7-kernel path.
// ===========================================================================
__global__ __launch_bounds__(256) void encoder_kernel(
    const float* __restrict__ x, const float* __restrict__ Win,
    const float* __restrict__ u0, float* __restrict__ h, float* __restrict__ ux)
{
    int vv = blockIdx.x * 256 + threadIdx.x;
    if (vv >= TOT) return;
    const int b = vv / Vv, lv = vv - b * Vv;
    float x0 = x[vv * 3 + 0], x1 = x[vv * 3 + 1], x2 = x[vv * 3 + 2];
    float hv[16];
#pragma unroll
    for (int c = 0; c < 16; c++) {
        float s = x0 * Win[c] + x1 * Win[16 + c] + x2 * Win[32 + c];
        hv[c] = fmaxf(s, 0.0f);
    }
    float4* hw = reinterpret_cast<float4*>(&h[(size_t)b * HS16 + (size_t)lv * 16]);
#pragma unroll
    for (int j = 0; j < 4; j++)
        hw[j] = make_float4(hv[4 * j], hv[4 * j + 1], hv[4 * j + 2], hv[4 * j + 3]);
#pragma unroll
    for (int k = 0; k < KK; k++) {
        float s = 0.0f;
#pragma unroll
        for (int c = 0; c < 16; c++) s = fmaf(hv[c], u0[c * KK + k], s);
        ux[(size_t)b * UXS + (size_t)lv * UXP + k] = s;
    }
}

template<int CIN, int COUT, bool LAST, int HSI, int HSO>
__global__ __launch_bounds__(256) void nlayer_kernel(
    const float* __restrict__ hin, const float* __restrict__ uxin,
    const int* __restrict__ adj, const float* __restrict__ W,
    const float* __restrict__ bvec, const float* __restrict__ cvec,
    const float* __restrict__ unx, float* __restrict__ hout,
    float* __restrict__ uxout, float* __restrict__ dout)
{
    const int tid = threadIdx.x;
    const int g = tid >> 4;
    const int t = tid & 15;
    const int vv = blockIdx.x * 16 + g;
    if (vv >= TOT) return;
    const int b = vv / Vv, lv = vv - b * Vv;
    int nb[NBK]; float rec;
    load_group(adj, lv, true, nb, rec);
    nlayer_step<CIN, COUT, LAST, false>(true, lv, t, nb, rec,
        hin + (size_t)b * HSI, uxin + (size_t)b * UXS,
        W, bvec, cvec, unx,
        LAST ? nullptr : hout + (size_t)b * HSO,
        LAST ? nullptr : uxout + (size_t)b * UXS,
        LAST ? dout + (size_t)b * Vv * 3 : nullptr);
}

// ---------------------------------------------------------------------------
extern "C" void kernel_launch(void* const* d_in, const int* in_sizes, int n_in,
                              void* d_out, int out_size, void* d_ws, size_t ws_size,
                              hipStream_t stream)
{
    const float* x    = (const float*)d_in[0];
    const int*   adj  = (const int*)  d_in[1];
    const float* Win  = (const float*)d_in[2];
    const float* Wout = (const float*)d_in[3];
    const float *W[6], *bb[6], *uu[6], *cc[6];
    for (int i = 0; i < 6; i++) {
        W[i]  = (const float*)d_in[4 + 4 * i];
        bb[i] = (const float*)d_in[5 + 4 * i];
        uu[i] = (const float*)d_in[6 + 4 * i];
        cc[i] = (const float*)d_in[7 + 4 * i];
    }
    float* out = (float*)d_out;

    char*  wsb = (char*)d_ws;
    Ctrl*  C   = (Ctrl*)wsb;
    float* p   = (float*)(wsb + 32768);
    float* h1 = p; p += (size_t)Bv * HS16;
    float* h2 = p; p += (size_t)Bv * HS16;
    float* h3 = p; p += (size_t)Bv * HS32;
    float* h4 = p; p += (size_t)Bv * HS16;
    float* h5 = p; p += (size_t)Bv * HS16;
    float* u1 = p; p += (size_t)Bv * UXS;
    float* u2 = p; p += (size_t)Bv * UXS;
    float* u3 = p; p += (size_t)Bv * UXS;
    float* u4 = p; p += (size_t)Bv * UXS;
    float* u5 = p; p += (size_t)Bv * UXS;

    int dev = 0, ncu = 0, maxb = 0;
    (void)hipGetDevice(&dev);
    (void)hipDeviceGetAttribute(&ncu, hipDeviceAttributeMultiprocessorCount, dev);
    hipError_t oe = hipOccupancyMaxActiveBlocksPerMultiprocessor(&maxb, fused_kernel, 256, 0);
    const bool use_fused = (oe == hipSuccess) && (ncu > 0) &&
                           ((long)maxb * ncu >= NBLK_F);

    if (use_fused) {
        (void)hipMemsetAsync(d_ws, 0, sizeof(Ctrl), stream);
        KArgs A;
        A.x = x; A.adj = adj; A.Win = Win; A.Wout = Wout;
        for (int i = 0; i < 6; i++) { A.W[i] = W[i]; A.bv[i] = bb[i]; A.uv[i] = uu[i]; A.cv[i] = cc[i]; }
        A.C = C;
        A.h1 = h1; A.h2 = h2; A.h3 = h3; A.h4 = h4; A.h5 = h5;
        A.u1 = u1; A.u2 = u2; A.u3 = u3; A.u4 = u4; A.u5 = u5;
        A.out = out;
        fused_kernel<<<NBLK_F, 256, 0, stream>>>(A);
        return;
    }

    // host fallback: 7-kernel chain (encoder + L0..L5)
    int nbv = (TOT + 255) / 256;
    encoder_kernel<<<nbv, 256, 0, stream>>>(x, Win, uu[0], h1, u1);
    int nb = (TOT + 15) / 16;
    nlayer_kernel<16, 16, false, HS16, HS16><<<nb, 256, 0, stream>>>(h1, u1, adj, W[0], bb[0], cc[0], uu[1], h2, u2, nullptr);
    nlayer_kernel<16, 16, false, HS16, HS16><<<nb, 256, 0, stream>>>(h2, u2, adj, W[1], bb[1], cc[1], uu[2], h4, u4, nullptr);
    nlayer_kernel<16, 32, false, HS16, HS32><<<nb, 256, 0, stream>>>(h4, u4, adj, W[2], bb[2], cc[2], uu[3], h3, u3, nullptr);
    nlayer_kernel<32, 16, false, HS32, HS16><<<nb, 256, 0, stream>>>(h3, u3, adj, W[3], bb[3], cc[3], uu[4], h5, u5, nullptr);
    nlayer_kernel<16, 16, false, HS16, HS16><<<nb, 256, 0, stream>>>(h5, u5, adj, W[4], bb[4], cc[4], uu[5], h1, u1, nullptr);
    nlayer_kernel<16, 3, true, HS16, HS16><<<nb, 256, 0, stream>>>(h1, u1, adj, W[5], bb[5], cc[5], Wout, nullptr, nullptr, out);
}

// Round 7
// 133.143 us; speedup vs baseline: 1.1828x; 1.1828x over previous
//
#include <hip/hip_runtime.h>

#define NBK 10
#define KK  9

constexpr int Bv  = 4;
constexpr int Vv  = 5023;
constexpr int TOT = Bv * Vv;   // 20092
constexpr int UXP = 12;        // padded ux row stride

// ---------------------------------------------------------------------------
// 16-lane merge-tree reduce (verified rounds 3-6): entry a[0..15] = per-lane
// partials of 16 outputs; exit: returns out[t] summed over the 16 lanes.
// ---------------------------------------------------------------------------
__device__ __forceinline__ float merge16(float* a, int t)
{
#pragma unroll
    for (int j = 0; j < 8; j++) {
        float send = (t & 8) ? a[j] : a[j + 8];
        float keep = (t & 8) ? a[j + 8] : a[j];
        a[j] = keep + __shfl_xor(send, 8, 16);
    }
#pragma unroll
    for (int j = 0; j < 4; j++) {
        float send = (t & 4) ? a[j] : a[j + 4];
        float keep = (t & 4) ? a[j + 4] : a[j];
        a[j] = keep + __shfl_xor(send, 4, 16);
    }
#pragma unroll
    for (int j = 0; j < 2; j++) {
        float send = (t & 2) ? a[j] : a[j + 2];
        float keep = (t & 2) ? a[j + 2] : a[j];
        a[j] = keep + __shfl_xor(send, 2, 16);
    }
    {
        float send = (t & 1) ? a[0] : a[1];
        float keep = (t & 1) ? a[1] : a[0];
        a[0] = keep + __shfl_xor(send, 1, 16);
    }
    return a[0];
}

// ---------------------------------------------------------------------------
// K1: encoder folded into layer 0 (verified math from round-4 timed path).
// h0 recomputed from x per gather; outputs h1 = L0(h0), ux1 = h1 @ u1.
// Zero LDS, zero barriers; one 16-lane group per vertex.
// ---------------------------------------------------------------------------
__global__ __launch_bounds__(256) void enc_l0_kernel(
    const float* __restrict__ x,     // [TOT,3]
    const int*   __restrict__ adj,   // [Vv,NBK]
    const float* __restrict__ Win,   // [3,16]
    const float* __restrict__ u0,    // [16,9]   (uu[0], logits map)
    const float* __restrict__ W,     // [16,9,16] (W[0])
    const float* __restrict__ bvec,  // [16]
    const float* __restrict__ cvec,  // [9]
    const float* __restrict__ unx,   // [16,9]   (uu[1], next layer's u)
    float* __restrict__ hout,        // [TOT,16]
    float* __restrict__ uxout)       // [TOT,UXP]
{
    const int tid = threadIdx.x;
    const int g = tid >> 4;
    const int t = tid & 15;
    const int vv = blockIdx.x * 16 + g;
    if (vv >= TOT) return;
    const int b = vv / Vv;
    const int v = vv - b * Vv;
    const float* xB = x + (size_t)b * Vv * 3;

    int nb[NBK];
    const int2* arow = reinterpret_cast<const int2*>(&adj[v * NBK]);
#pragma unroll
    for (int j = 0; j < 5; j++) { int2 p = arow[j]; nb[2 * j] = p.x; nb[2 * j + 1] = p.y; }
    int cnt = 0;
#pragma unroll
    for (int n = 0; n < NBK; n++) cnt += (nb[n] != 0) ? 1 : 0;
    const float rec = cnt ? (1.0f / (float)cnt) : 0.0f;

    // neighbor h0, owned channel t: relu(x_nb . Win[:,t])
    const float w0 = Win[t], w1 = Win[16 + t], w2 = Win[32 + t];
    float hn0[NBK];
#pragma unroll
    for (int n = 0; n < NBK; n++) {
        const int a = nb[n];
        float x0 = 0.f, x1 = 0.f, x2 = 0.f;
        if (a) {
            const float* xr = &xB[(size_t)(a - 1) * 3];
            x0 = xr[0]; x1 = xr[1]; x2 = xr[2];
        }
        hn0[n] = fmaxf(x0 * w0 + x1 * w1 + x2 * w2, 0.0f);
    }

    // softmax over k: lane t<10 handles neighbor t (verified layer0 math)
    float q[KK] = {};
    if (t < NBK) {
        const float* xo = &xB[(size_t)v * 3];
        const float xo0 = xo[0], xo1 = xo[1], xo2 = xo[2];
        const int a = nb[t];
        float xn0 = 0.f, xn1 = 0.f, xn2 = 0.f;
        if (a) {
            const float* xr = &xB[(size_t)(a - 1) * 3];
            xn0 = xr[0]; xn1 = xr[1]; xn2 = xr[2];
        }
        float hs[16];
#pragma unroll
        for (int c = 0; c < 16; c++) {
            const float ho = fmaxf(xo0 * Win[c] + xo1 * Win[16 + c] + xo2 * Win[32 + c], 0.0f);
            const float hn = fmaxf(xn0 * Win[c] + xn1 * Win[16 + c] + xn2 * Win[32 + c], 0.0f);
            hs[c] = ho + hn;
        }
        float lg[KK];
#pragma unroll
        for (int k = 0; k < KK; k++) {
            float s = cvec[k];
#pragma unroll
            for (int c = 0; c < 16; c++) s = fmaf(hs[c], u0[c * KK + k], s);
            lg[k] = s;
        }
        float m = lg[0];
#pragma unroll
        for (int k = 1; k < KK; k++) m = fmaxf(m, lg[k]);
        float sum = 0.0f;
#pragma unroll
        for (int k = 0; k < KK; k++) { q[k] = __expf(lg[k] - m); sum += q[k]; }
        const float r = 1.0f / sum;
#pragma unroll
        for (int k = 0; k < KK; k++) q[k] *= r;
    }

    // G-phase
    float g0[KK];
#pragma unroll
    for (int k = 0; k < KK; k++) g0[k] = 0.0f;
#pragma unroll
    for (int n = 0; n < NBK; n++) {
#pragma unroll
        for (int k = 0; k < KK; k++) {
            const float qnk = __shfl(q[k], n, 16);
            g0[k] = fmaf(qnk, hn0[n], g0[k]);
        }
    }

    // E-phase: acc[o] += g[k] * W[c=t][k][o] (float4 from L1/L2)
    float acc[16] = {};
#pragma unroll
    for (int k = 0; k < KK; k++) {
        const float4* wr = reinterpret_cast<const float4*>(&W[((size_t)t * KK + k) * 16]);
#pragma unroll
        for (int o4 = 0; o4 < 4; o4++) {
            const float4 w = wr[o4];
            acc[4 * o4 + 0] = fmaf(g0[k], w.x, acc[4 * o4 + 0]);
            acc[4 * o4 + 1] = fmaf(g0[k], w.y, acc[4 * o4 + 1]);
            acc[4 * o4 + 2] = fmaf(g0[k], w.z, acc[4 * o4 + 2]);
            acc[4 * o4 + 3] = fmaf(g0[k], w.w, acc[4 * o4 + 3]);
        }
    }

    const float o0 = merge16(acc, t);
    const float h0v = fmaxf(fmaf(o0, rec, bvec[t]), 0.0f);
    hout[(size_t)vv * 16 + t] = h0v;

    // fused ux for next layer
    float uxv = 0.0f;
#pragma unroll
    for (int o = 0; o < 16; o++) {
        const float hb = __shfl(h0v, o, 16);
        if (t < KK) uxv = fmaf(hb, unx[o * KK + t], uxv);
    }
    if (t < KK) uxout[(size_t)vv * UXP + t] = uxv;
}

// ---------------------------------------------------------------------------
// K2..K6: round-1 verified LDS-body NLayer (ux stride changed 9 -> UXP).
// 16 lanes per vertex, 16 vertices per 256-thread block.
// ---------------------------------------------------------------------------
template<int CIN, int COUT, bool LAST>
__global__ __launch_bounds__(256) void nlayer_kernel(
    const float* __restrict__ hin,
    const float* __restrict__ uxin,
    const int*   __restrict__ adj,    // [Vv,NBK]
    const float* __restrict__ W,      // [CIN,KK,COUT]
    const float* __restrict__ bvec,   // [COUT]
    const float* __restrict__ cvec,   // [KK]
    const float* __restrict__ unext,  // [COUT,KK]  (or Wout [3,3] if LAST)
    float* __restrict__ hout,
    float* __restrict__ uxout,
    float* __restrict__ dout)
{
    constexpr int CP = CIN + 4;   // pad so group stride != 0 mod 32 banks
    constexpr int WP = CIN + 1;   // odd stride -> conflict-free staging+reads

    __shared__ __align__(16) float s_hnb[16][NBK][CP];
    __shared__ float s_lg[16][NBK][KK];   // logits -> q
    __shared__ float s_uxs[16][KK];
    __shared__ int   s_adj[16][NBK];
    __shared__ float s_rec[16];
    __shared__ float s_hnew[16][COUT];
    __shared__ float s_w[KK][COUT][WP];   // W transposed: [k][o][c]

    const int tid = threadIdx.x;
    const int g = tid >> 4;
    const int t = tid & 15;
    const int vv = blockIdx.x * 16 + g;
    const bool act = vv < TOT;
    int b = 0, v = 0;
    if (act) { b = vv / Vv; v = vv - b * Vv; }

    // Stage W transposed into LDS (global reads coalesced; odd LDS stride)
    for (int i = tid; i < CIN * KK * COUT; i += 256) {
        int c = i / (KK * COUT);
        int rem = i - c * (KK * COUT);
        int k = rem / COUT;
        int o = rem - k * COUT;
        s_w[k][o][c] = W[i];
    }

    if (act) {
        if (t < NBK) s_adj[g][t] = adj[v * NBK + t];
        if (t < KK)  s_uxs[g][t] = uxin[(size_t)vv * UXP + t];
    }
    __syncthreads();

    if (act && t == 0) {
        int cnt = 0;
#pragma unroll
        for (int n = 0; n < NBK; n++) cnt += (s_adj[g][n] != 0) ? 1 : 0;
        s_rec[g] = (cnt > 0) ? (1.0f / (float)cnt) : 0.0f;
    }

    if (act) {
        // Gather neighbor features h_nb -> LDS (float4)
        constexpr int U = NBK * CIN / 4;
        for (int j = t; j < U; j += 16) {
            int n  = j / (CIN / 4);
            int c4 = j - n * (CIN / 4);
            int a = s_adj[g][n];
            float4 val = {0.0f, 0.0f, 0.0f, 0.0f};
            if (a != 0)
                val = *reinterpret_cast<const float4*>(
                    &hin[((size_t)b * Vv + (a - 1)) * CIN + c4 * 4]);
            *reinterpret_cast<float4*>(&s_hnb[g][n][c4 * 4]) = val;
        }
        // Gather neighbor ux, build logits
        for (int j = t; j < NBK * KK; j += 16) {
            int n = j / KK;
            int k = j - n * KK;
            int a = s_adj[g][n];
            float uxn = (a != 0) ? uxin[((size_t)b * Vv + (a - 1)) * UXP + k] : 0.0f;
            s_lg[g][n][k] = s_uxs[g][k] + uxn + cvec[k];
        }
    }
    __syncthreads();

    // Softmax over k, per neighbor (lanes t<10)
    if (act && t < NBK) {
        float m = -1e30f;
#pragma unroll
        for (int k = 0; k < KK; k++) m = fmaxf(m, s_lg[g][t][k]);
        float e[KK];
        float s = 0.0f;
#pragma unroll
        for (int k = 0; k < KK; k++) { e[k] = __expf(s_lg[g][t][k] - m); s += e[k]; }
        float r = 1.0f / s;
#pragma unroll
        for (int k = 0; k < KK; k++) s_lg[g][t][k] = e[k] * r;
    }
    __syncthreads();

    // G[k][c] for owned channels c = t (and t+16 if CIN==32)
    float g0[KK], g1[KK];
#pragma unroll
    for (int k = 0; k < KK; k++) { g0[k] = 0.0f; g1[k] = 0.0f; }
    if (act) {
#pragma unroll
        for (int n = 0; n < NBK; n++) {
            float h0 = s_hnb[g][n][t];
            float h1 = (CIN == 32) ? s_hnb[g][n][t + 16] : 0.0f;
#pragma unroll
            for (int k = 0; k < KK; k++) {
                float qv = s_lg[g][n][k];
                g0[k] = fmaf(qv, h0, g0[k]);
                if (CIN == 32) g1[k] = fmaf(qv, h1, g1[k]);
            }
        }
    }

    // E: partial out[o] from owned channels, then 16-lane butterfly reduce
    float acc[COUT];
#pragma unroll
    for (int o = 0; o < COUT; o++) acc[o] = 0.0f;
    if (act) {
#pragma unroll
        for (int k = 0; k < KK; k++) {
#pragma unroll
            for (int o = 0; o < COUT; o++) {
                acc[o] = fmaf(g0[k], s_w[k][o][t], acc[o]);
                if (CIN == 32) acc[o] = fmaf(g1[k], s_w[k][o][t + 16], acc[o]);
            }
        }
    }
#pragma unroll
    for (int o = 0; o < COUT; o++) {
        acc[o] += __shfl_xor(acc[o], 1, 16);
        acc[o] += __shfl_xor(acc[o], 2, 16);
        acc[o] += __shfl_xor(acc[o], 4, 16);
        acc[o] += __shfl_xor(acc[o], 8, 16);
    }

    // Epilogue: scale by recip, +bias, relu; write h / s_hnew
    if (act) {
        float rec = s_rec[g];
        constexpr int O0 = (COUT < 16) ? COUT : 16;
        if (t < O0) {
            float val = fmaxf(acc[t] * rec + bvec[t], 0.0f);
            if (!LAST) hout[(size_t)vv * COUT + t] = val;
            s_hnew[g][t] = val;
        }
        if (COUT == 32) {
            float val = fmaxf(acc[t + 16] * rec + bvec[t + 16], 0.0f);
            hout[(size_t)vv * COUT + t + 16] = val;
            s_hnew[g][t + 16] = val;
        }
    }
    __syncthreads();

    if (!LAST) {
        // Fused ux for next layer: ux[k] = sum_o hnew[o] * unext[o,k]
        if (act && t < KK) {
            float s = 0.0f;
#pragma unroll
            for (int o = 0; o < COUT; o++)
                s = fmaf(s_hnew[g][o], unext[o * KK + t], s);
            uxout[(size_t)vv * UXP + t] = s;
        }
    } else {
        // Fused decoder: dout = hnew @ Wout  (3x3)
        if (act && t < 3) {
            float s = 0.0f;
#pragma unroll
            for (int j = 0; j < 3; j++)
                s = fmaf(s_hnew[g][j], unext[j * 3 + t], s);
            dout[(size_t)vv * 3 + t] = s;
        }
    }
}

// ---------------------------------------------------------------------------
extern "C" void kernel_launch(void* const* d_in, const int* in_sizes, int n_in,
                              void* d_out, int out_size, void* d_ws, size_t ws_size,
                              hipStream_t stream)
{
    const float* x    = (const float*)d_in[0];
    const int*   adj  = (const int*)  d_in[1];
    const float* Win  = (const float*)d_in[2];
    const float* Wout = (const float*)d_in[3];
    const float *W[6], *bb[6], *uu[6], *cc[6];
    for (int i = 0; i < 6; i++) {
        W[i]  = (const float*)d_in[4 + 4 * i];
        bb[i] = (const float*)d_in[5 + 4 * i];
        uu[i] = (const float*)d_in[6 + 4 * i];
        cc[i] = (const float*)d_in[7 + 4 * i];
    }
    float* out = (float*)d_out;

    // Workspace (floats): h1,h2 [TOT*16], h3 [TOT*32], h4,h5 [TOT*16],
    // ux1..ux5 [TOT*UXP]
    float* p  = (float*)d_ws;
    float* h1 = p; p += (size_t)TOT * 16;
    float* h2 = p; p += (size_t)TOT * 16;
    float* h3 = p; p += (size_t)TOT * 32;
    float* h4 = p; p += (size_t)TOT * 16;
    float* h5 = p; p += (size_t)TOT * 16;
    float* u1 = p; p += (size_t)TOT * UXP;
    float* u2 = p; p += (size_t)TOT * UXP;
    float* u3 = p; p += (size_t)TOT * UXP;
    float* u4 = p; p += (size_t)TOT * UXP;
    float* u5 = p; p += (size_t)TOT * UXP;

    const int nb = (TOT + 15) / 16;   // 1256 blocks, 16 vertices/block

    // K1: encoder + layer0 fused -> h1, ux1(= h1 @ uu[1])
    enc_l0_kernel<<<nb, 256, 0, stream>>>(x, adj, Win, uu[0], W[0], bb[0], cc[0],
                                          uu[1], h1, u1);
    // K2..K6: layers 1..5 (round-1 verified bodies)
    nlayer_kernel<16, 16, false><<<nb, 256, 0, stream>>>(h1, u1, adj, W[1], bb[1], cc[1], uu[2], h2, u2, nullptr);
    nlayer_kernel<16, 32, false><<<nb, 256, 0, stream>>>(h2, u2, adj, W[2], bb[2], cc[2], uu[3], h3, u3, nullptr);
    nlayer_kernel<32, 16, false><<<nb, 256, 0, stream>>>(h3, u3, adj, W[3], bb[3], cc[3], uu[4], h4, u4, nullptr);
    nlayer_kernel<16, 16, false><<<nb, 256, 0, stream>>>(h4, u4, adj, W[4], bb[4], cc[4], uu[5], h5, u5, nullptr);
    nlayer_kernel<16, 3, true ><<<nb, 256, 0, stream>>>(h5, u5, adj, W[5], bb[5], cc[5], Wout, nullptr, nullptr, out);
}

// Round 8
// 79.488 us; speedup vs baseline: 1.9812x; 1.6750x over previous
//
#include <hip/hip_runtime.h>

#define NBK 10
#define KK  9

constexpr int Bv  = 4;
constexpr int Vv  = 5023;
constexpr int TOT = Bv * Vv;   // 20092
constexpr int UXP = 12;        // padded ux row stride (float4-friendly)

// ---------------------------------------------------------------------------
// 16-lane merge-tree reduce (verified rounds 3-7): entry a[0..15] = per-lane
// partials of 16 outputs; exit: returns out[t] summed over the 16 lanes.
// ---------------------------------------------------------------------------
__device__ __forceinline__ float merge16(float* a, int t)
{
#pragma unroll
    for (int j = 0; j < 8; j++) {
        float send = (t & 8) ? a[j] : a[j + 8];
        float keep = (t & 8) ? a[j + 8] : a[j];
        a[j] = keep + __shfl_xor(send, 8, 16);
    }
#pragma unroll
    for (int j = 0; j < 4; j++) {
        float send = (t & 4) ? a[j] : a[j + 4];
        float keep = (t & 4) ? a[j + 4] : a[j];
        a[j] = keep + __shfl_xor(send, 4, 16);
    }
#pragma unroll
    for (int j = 0; j < 2; j++) {
        float send = (t & 2) ? a[j] : a[j + 2];
        float keep = (t & 2) ? a[j + 2] : a[j];
        a[j] = keep + __shfl_xor(send, 2, 16);
    }
    {
        float send = (t & 1) ? a[0] : a[1];
        float keep = (t & 1) ? a[1] : a[0];
        a[0] = keep + __shfl_xor(send, 1, 16);
    }
    return a[0];
}

// ---------------------------------------------------------------------------
// K1: encoder folded into layer 0 (verified round-7). Zero LDS, zero barriers.
// ---------------------------------------------------------------------------
__global__ __launch_bounds__(256) void enc_l0_kernel(
    const float* __restrict__ x,     // [TOT,3]
    const int*   __restrict__ adj,   // [Vv,NBK]
    const float* __restrict__ Win,   // [3,16]
    const float* __restrict__ u0,    // [16,9]
    const float* __restrict__ W,     // [16,9,16] (W[0])
    const float* __restrict__ bvec,  // [16]
    const float* __restrict__ cvec,  // [9]
    const float* __restrict__ unx,   // [16,9]   (uu[1])
    float* __restrict__ hout,        // [TOT,16]
    float* __restrict__ uxout)       // [TOT,UXP]
{
    const int tid = threadIdx.x;
    const int g = tid >> 4;
    const int t = tid & 15;
    const int vv = blockIdx.x * 16 + g;
    if (vv >= TOT) return;
    const int b = vv / Vv;
    const int v = vv - b * Vv;
    const float* xB = x + (size_t)b * Vv * 3;

    int nb[NBK];
    const int2* arow = reinterpret_cast<const int2*>(&adj[v * NBK]);
#pragma unroll
    for (int j = 0; j < 5; j++) { int2 p = arow[j]; nb[2 * j] = p.x; nb[2 * j + 1] = p.y; }
    int cnt = 0;
#pragma unroll
    for (int n = 0; n < NBK; n++) cnt += (nb[n] != 0) ? 1 : 0;
    const float rec = cnt ? (1.0f / (float)cnt) : 0.0f;

    const float w0 = Win[t], w1 = Win[16 + t], w2 = Win[32 + t];
    float hn0[NBK];
#pragma unroll
    for (int n = 0; n < NBK; n++) {
        const int a = nb[n];
        float x0 = 0.f, x1 = 0.f, x2 = 0.f;
        if (a) {
            const float* xr = &xB[(size_t)(a - 1) * 3];
            x0 = xr[0]; x1 = xr[1]; x2 = xr[2];
        }
        hn0[n] = fmaxf(x0 * w0 + x1 * w1 + x2 * w2, 0.0f);
    }

    float q[KK] = {};
    if (t < NBK) {
        const float* xo = &xB[(size_t)v * 3];
        const float xo0 = xo[0], xo1 = xo[1], xo2 = xo[2];
        const int a = nb[t];
        float xn0 = 0.f, xn1 = 0.f, xn2 = 0.f;
        if (a) {
            const float* xr = &xB[(size_t)(a - 1) * 3];
            xn0 = xr[0]; xn1 = xr[1]; xn2 = xr[2];
        }
        float hs[16];
#pragma unroll
        for (int c = 0; c < 16; c++) {
            const float ho = fmaxf(xo0 * Win[c] + xo1 * Win[16 + c] + xo2 * Win[32 + c], 0.0f);
            const float hn = fmaxf(xn0 * Win[c] + xn1 * Win[16 + c] + xn2 * Win[32 + c], 0.0f);
            hs[c] = ho + hn;
        }
        float lg[KK];
#pragma unroll
        for (int k = 0; k < KK; k++) {
            float s = cvec[k];
#pragma unroll
            for (int c = 0; c < 16; c++) s = fmaf(hs[c], u0[c * KK + k], s);
            lg[k] = s;
        }
        float m = lg[0];
#pragma unroll
        for (int k = 1; k < KK; k++) m = fmaxf(m, lg[k]);
        float sum = 0.0f;
#pragma unroll
        for (int k = 0; k < KK; k++) { q[k] = __expf(lg[k] - m); sum += q[k]; }
        const float r = 1.0f / sum;
#pragma unroll
        for (int k = 0; k < KK; k++) q[k] *= r;
    }

    float g0[KK];
#pragma unroll
    for (int k = 0; k < KK; k++) g0[k] = 0.0f;
#pragma unroll
    for (int n = 0; n < NBK; n++) {
#pragma unroll
        for (int k = 0; k < KK; k++) {
            const float qnk = __shfl(q[k], n, 16);
            g0[k] = fmaf(qnk, hn0[n], g0[k]);
        }
    }

    float acc[16] = {};
#pragma unroll
    for (int k = 0; k < KK; k++) {
        const float4* wr = reinterpret_cast<const float4*>(&W[((size_t)t * KK + k) * 16]);
#pragma unroll
        for (int o4 = 0; o4 < 4; o4++) {
            const float4 w = wr[o4];
            acc[4 * o4 + 0] = fmaf(g0[k], w.x, acc[4 * o4 + 0]);
            acc[4 * o4 + 1] = fmaf(g0[k], w.y, acc[4 * o4 + 1]);
            acc[4 * o4 + 2] = fmaf(g0[k], w.z, acc[4 * o4 + 2]);
            acc[4 * o4 + 3] = fmaf(g0[k], w.w, acc[4 * o4 + 3]);
        }
    }

    const float o0 = merge16(acc, t);
    const float h0v = fmaxf(fmaf(o0, rec, bvec[t]), 0.0f);
    hout[(size_t)vv * 16 + t] = h0v;

    float uxv = 0.0f;
#pragma unroll
    for (int o = 0; o < 16; o++) {
        const float hb = __shfl(h0v, o, 16);
        if (t < KK) uxv = fmaf(hb, unx[o * KK + t], uxv);
    }
    if (t < KK) uxout[(size_t)vv * UXP + t] = uxv;
}

// ---------------------------------------------------------------------------
// K2..K6: ONE-barrier NLayer. All per-vertex state is wave-local (registers +
// wave-private s_q); only W staging needs the block barrier. W in LDS as
// [k][c][o] with padded o-stride (COUTP) so E-phase is ds_read_b128 at
// <=2-way bank conflicts (free). h gathers register-direct (16 lanes read one
// 64B row -> coalesced). hnew->ux broadcast via shuffles, no LDS, no barrier.
// ---------------------------------------------------------------------------
template<int CIN, int COUT, bool LAST>
__global__ __launch_bounds__(256) void nlayer_kernel(
    const float* __restrict__ hin,    // [TOT,CIN]
    const float* __restrict__ uxin,   // [TOT,UXP]
    const int*   __restrict__ adj,    // [Vv,NBK]
    const float* __restrict__ W,      // [CIN,KK,COUT]
    const float* __restrict__ bvec,   // [COUT]
    const float* __restrict__ cvec,   // [KK]
    const float* __restrict__ unx,    // [COUT,KK]  (or Wout [3,3] if LAST)
    float* __restrict__ hout,
    float* __restrict__ uxout,
    float* __restrict__ dout)
{
    constexpr int COUTP = (COUT == 32) ? 36 : ((COUT == 16) ? 20 : 4);

    __shared__ __align__(16) float s_w[KK * CIN * COUTP];  // [k][c][o] padded
    __shared__ __align__(16) float s_q[16][NBK][12];       // wave-private q

    const int tid = threadIdx.x;

    // --- stage W (block-cooperative; the ONLY barrier in this kernel) ---
    for (int i = tid; i < CIN * KK * COUT; i += 256) {
        const int c   = i / (KK * COUT);
        const int rem = i - c * (KK * COUT);
        const int k   = rem / COUT;
        const int o   = rem - k * COUT;
        s_w[(k * CIN + c) * COUTP + o] = W[i];
    }
    __syncthreads();

    const int g = tid >> 4;
    const int t = tid & 15;
    const int vv = blockIdx.x * 16 + g;
    if (vv >= TOT) return;               // after the single barrier: safe
    const int b = vv / Vv;
    const int v = vv - b * Vv;
    const float* hinB  = hin  + (size_t)b * Vv * CIN;
    const float* uxinB = uxin + (size_t)b * Vv * UXP;

    // --- adjacency row + recip (registers, broadcast L1 reads) ---
    int nb[NBK];
    const int2* arow = reinterpret_cast<const int2*>(&adj[v * NBK]);
#pragma unroll
    for (int j = 0; j < 5; j++) { int2 p = arow[j]; nb[2 * j] = p.x; nb[2 * j + 1] = p.y; }
    int cnt = 0;
#pragma unroll
    for (int n = 0; n < NBK; n++) cnt += (nb[n] != 0) ? 1 : 0;
    const float rec = cnt ? (1.0f / (float)cnt) : 0.0f;

    // --- register gather of neighbor features for owned channel(s) ---
    float hn0[NBK], hn1[NBK];
#pragma unroll
    for (int n = 0; n < NBK; n++) {
        const int a = nb[n];
        const float* hr = &hinB[(size_t)(a - 1) * CIN];
        hn0[n] = a ? hr[t] : 0.0f;
        if constexpr (CIN == 32) hn1[n] = a ? hr[t + 16] : 0.0f;
        else                     hn1[n] = 0.0f;
    }

    // --- softmax over k: lane t<10 handles neighbor t, in registers -> s_q ---
    if (t < NBK) {
        const float* su = &uxinB[(size_t)v * UXP];
        const float4 s0 = *reinterpret_cast<const float4*>(su);
        const float4 s1 = *reinterpret_cast<const float4*>(su + 4);
        const float  s8 = su[8];
        const int a = nb[t];
        float4 n0 = make_float4(0.f, 0.f, 0.f, 0.f), n1 = n0;
        float  n8 = 0.0f;
        if (a) {
            const float* nu = &uxinB[(size_t)(a - 1) * UXP];
            n0 = *reinterpret_cast<const float4*>(nu);
            n1 = *reinterpret_cast<const float4*>(nu + 4);
            n8 = nu[8];
        }
        float lg[KK] = { s0.x + n0.x + cvec[0], s0.y + n0.y + cvec[1],
                         s0.z + n0.z + cvec[2], s0.w + n0.w + cvec[3],
                         s1.x + n1.x + cvec[4], s1.y + n1.y + cvec[5],
                         s1.z + n1.z + cvec[6], s1.w + n1.w + cvec[7],
                         s8 + n8 + cvec[8] };
        float m = lg[0];
#pragma unroll
        for (int k = 1; k < KK; k++) m = fmaxf(m, lg[k]);
        float e[KK], sum = 0.0f;
#pragma unroll
        for (int k = 0; k < KK; k++) { e[k] = __expf(lg[k] - m); sum += e[k]; }
        const float r = 1.0f / sum;
        *reinterpret_cast<float4*>(&s_q[g][t][0]) =
            make_float4(e[0] * r, e[1] * r, e[2] * r, e[3] * r);
        *reinterpret_cast<float4*>(&s_q[g][t][4]) =
            make_float4(e[4] * r, e[5] * r, e[6] * r, e[7] * r);
        s_q[g][t][8] = e[8] * r;
    }
    // wave-local LDS RAW: compiler-inserted lgkmcnt orders write->read; the
    // writer lanes (t<10) and reader lanes are the same wave, no barrier.

    // --- G-phase: g[k] = sum_n q[n][k] * h_nb[n][c_own] (broadcast reads) ---
    float g0[KK], g1[KK];
#pragma unroll
    for (int k = 0; k < KK; k++) { g0[k] = 0.0f; g1[k] = 0.0f; }
#pragma unroll
    for (int n = 0; n < NBK; n++) {
        const float4 qa = *reinterpret_cast<const float4*>(&s_q[g][n][0]);
        const float4 qb = *reinterpret_cast<const float4*>(&s_q[g][n][4]);
        const float  q8 = s_q[g][n][8];
        const float h0 = hn0[n];
        g0[0] = fmaf(qa.x, h0, g0[0]); g0[1] = fmaf(qa.y, h0, g0[1]);
        g0[2] = fmaf(qa.z, h0, g0[2]); g0[3] = fmaf(qa.w, h0, g0[3]);
        g0[4] = fmaf(qb.x, h0, g0[4]); g0[5] = fmaf(qb.y, h0, g0[5]);
        g0[6] = fmaf(qb.z, h0, g0[6]); g0[7] = fmaf(qb.w, h0, g0[7]);
        g0[8] = fmaf(q8,   h0, g0[8]);
        if constexpr (CIN == 32) {
            const float h1 = hn1[n];
            g1[0] = fmaf(qa.x, h1, g1[0]); g1[1] = fmaf(qa.y, h1, g1[1]);
            g1[2] = fmaf(qa.z, h1, g1[2]); g1[3] = fmaf(qa.w, h1, g1[3]);
            g1[4] = fmaf(qb.x, h1, g1[4]); g1[5] = fmaf(qb.y, h1, g1[5]);
            g1[6] = fmaf(qb.z, h1, g1[6]); g1[7] = fmaf(qb.w, h1, g1[7]);
            g1[8] = fmaf(q8,   h1, g1[8]);
        }
    }

    if constexpr (!LAST) {
        // --- E-phase: ds_read_b128 rows of s_w[k][c=t][*] ---
        float acc[COUT] = {};
#pragma unroll
        for (int k = 0; k < KK; k++) {
            const float g0k = g0[k];
            const float* wr = &s_w[(k * CIN + t) * COUTP];
#pragma unroll
            for (int o4 = 0; o4 < COUT / 4; o4++) {
                const float4 w = *reinterpret_cast<const float4*>(&wr[4 * o4]);
                acc[4 * o4 + 0] = fmaf(g0k, w.x, acc[4 * o4 + 0]);
                acc[4 * o4 + 1] = fmaf(g0k, w.y, acc[4 * o4 + 1]);
                acc[4 * o4 + 2] = fmaf(g0k, w.z, acc[4 * o4 + 2]);
                acc[4 * o4 + 3] = fmaf(g0k, w.w, acc[4 * o4 + 3]);
            }
            if constexpr (CIN == 32) {
                const float g1k = g1[k];
                const float* wr2 = &s_w[(k * CIN + t + 16) * COUTP];
#pragma unroll
                for (int o4 = 0; o4 < COUT / 4; o4++) {
                    const float4 w = *reinterpret_cast<const float4*>(&wr2[4 * o4]);
                    acc[4 * o4 + 0] = fmaf(g1k, w.x, acc[4 * o4 + 0]);
                    acc[4 * o4 + 1] = fmaf(g1k, w.y, acc[4 * o4 + 1]);
                    acc[4 * o4 + 2] = fmaf(g1k, w.z, acc[4 * o4 + 2]);
                    acc[4 * o4 + 3] = fmaf(g1k, w.w, acc[4 * o4 + 3]);
                }
            }
        }

        const float o0 = merge16(acc, t);
        const float h0v = fmaxf(fmaf(o0, rec, bvec[t]), 0.0f);
        hout[(size_t)vv * COUT + t] = h0v;
        float h1v = 0.0f;
        if constexpr (COUT == 32) {
            const float o1 = merge16(acc + 16, t);
            h1v = fmaxf(fmaf(o1, rec, bvec[t + 16]), 0.0f);
            hout[(size_t)vv * COUT + 16 + t] = h1v;
        }

        // --- fused ux for next layer (shuffle broadcast, no LDS/barrier) ---
        float uxv = 0.0f;
#pragma unroll
        for (int o = 0; o < 16; o++) {
            const float hb = __shfl(h0v, o, 16);
            if (t < KK) uxv = fmaf(hb, unx[o * KK + t], uxv);
        }
        if constexpr (COUT == 32) {
#pragma unroll
            for (int o = 0; o < 16; o++) {
                const float hb = __shfl(h1v, o, 16);
                if (t < KK) uxv = fmaf(hb, unx[(o + 16) * KK + t], uxv);
            }
        }
        if (t < KK) uxout[(size_t)vv * UXP + t] = uxv;
    } else {
        // COUT == 3: fused decoder
        float acc[3] = {};
#pragma unroll
        for (int k = 0; k < KK; k++) {
            const float4 w = *reinterpret_cast<const float4*>(&s_w[(k * CIN + t) * COUTP]);
            acc[0] = fmaf(g0[k], w.x, acc[0]);
            acc[1] = fmaf(g0[k], w.y, acc[1]);
            acc[2] = fmaf(g0[k], w.z, acc[2]);
        }
#pragma unroll
        for (int o = 0; o < 3; o++) {
            acc[o] += __shfl_xor(acc[o], 1, 16);
            acc[o] += __shfl_xor(acc[o], 2, 16);
            acc[o] += __shfl_xor(acc[o], 4, 16);
            acc[o] += __shfl_xor(acc[o], 8, 16);
        }
        float hnew[3];
#pragma unroll
        for (int o = 0; o < 3; o++)
            hnew[o] = fmaxf(fmaf(acc[o], rec, bvec[o]), 0.0f);
        if (t < 3) {
            float s = 0.0f;
#pragma unroll
            for (int j = 0; j < 3; j++)
                s = fmaf(hnew[j], unx[j * 3 + t], s);
            dout[(size_t)vv * 3 + t] = s;
        }
    }
}

// ---------------------------------------------------------------------------
extern "C" void kernel_launch(void* const* d_in, const int* in_sizes, int n_in,
                              void* d_out, int out_size, void* d_ws, size_t ws_size,
                              hipStream_t stream)
{
    const float* x    = (const float*)d_in[0];
    const int*   adj  = (const int*)  d_in[1];
    const float* Win  = (const float*)d_in[2];
    const float* Wout = (const float*)d_in[3];
    const float *W[6], *bb[6], *uu[6], *cc[6];
    for (int i = 0; i < 6; i++) {
        W[i]  = (const float*)d_in[4 + 4 * i];
        bb[i] = (const float*)d_in[5 + 4 * i];
        uu[i] = (const float*)d_in[6 + 4 * i];
        cc[i] = (const float*)d_in[7 + 4 * i];
    }
    float* out = (float*)d_out;

    float* p  = (float*)d_ws;
    float* h1 = p; p += (size_t)TOT * 16;
    float* h2 = p; p += (size_t)TOT * 16;
    float* h3 = p; p += (size_t)TOT * 32;
    float* h4 = p; p += (size_t)TOT * 16;
    float* h5 = p; p += (size_t)TOT * 16;
    float* u1 = p; p += (size_t)TOT * UXP;
    float* u2 = p; p += (size_t)TOT * UXP;
    float* u3 = p; p += (size_t)TOT * UXP;
    float* u4 = p; p += (size_t)TOT * UXP;
    float* u5 = p; p += (size_t)TOT * UXP;

    const int nb = (TOT + 15) / 16;   // 1256 blocks, 16 vertices/block

    enc_l0_kernel<<<nb, 256, 0, stream>>>(x, adj, Win, uu[0], W[0], bb[0], cc[0],
                                          uu[1], h1, u1);
    nlayer_kernel<16, 16, false><<<nb, 256, 0, stream>>>(h1, u1, adj, W[1], bb[1], cc[1], uu[2], h2, u2, nullptr);
    nlayer_kernel<16, 32, false><<<nb, 256, 0, stream>>>(h2, u2, adj, W[2], bb[2], cc[2], uu[3], h3, u3, nullptr);
    nlayer_kernel<32, 16, false><<<nb, 256, 0, stream>>>(h3, u3, adj, W[3], bb[3], cc[3], uu[4], h4, u4, nullptr);
    nlayer_kernel<16, 16, false><<<nb, 256, 0, stream>>>(h4, u4, adj, W[4], bb[4], cc[4], uu[5], h5, u5, nullptr);
    nlayer_kernel<16, 3, true ><<<nb, 256, 0, stream>>>(h5, u5, adj, W[5], bb[5], cc[5], Wout, nullptr, nullptr, out);
}